// Round 1
// baseline (399.018 us; speedup 1.0000x reference)
//
#include <hip/hip_runtime.h>
#include <hip/hip_bf16.h>

#define N_NODES 50000
#define N_EDGES 800000
#define DIM 128
#define NTILES (N_EDGES / 64)   // 12500 exactly

typedef __bf16 bf16x8 __attribute__((ext_vector_type(8)));
typedef float f32x4 __attribute__((ext_vector_type(4)));
typedef unsigned int u32x4 __attribute__((ext_vector_type(4)));

__device__ __forceinline__ unsigned short f2bf(float f) {
    unsigned u = __float_as_uint(f);
    u += 0x7fffu + ((u >> 16) & 1u);          // round-to-nearest-even
    return (unsigned short)(u >> 16);
}

// ---- convert W2 [256][128] -> W2t [128 n][256 k] bf16; W3 [128][128] -> W3t [128 n][128 k]
__global__ void convert_w_kernel(const float* __restrict__ W2, const float* __restrict__ W3,
                                 unsigned short* __restrict__ W2t, unsigned short* __restrict__ W3t) {
    int i = blockIdx.x * 256 + threadIdx.x;   // grid covers exactly 49152
    if (i < 2 * DIM * DIM) {
        int k = i >> 7, n = i & 127;
        W2t[n * 256 + k] = f2bf(W2[i]);
    } else {
        int j = i - 2 * DIM * DIM;
        int k = j >> 7, n = j & 127;
        W3t[n * 128 + k] = f2bf(W3[j]);
    }
}

// ---- lin1: hbf[N][128] = bf16(x @ W1 + b1), MFMA 16x16x32, W1 transposed in LDS
__global__ __launch_bounds__(256, 2) void lin1_kernel(const float* __restrict__ x,
        const float* __restrict__ W1, const float* __restrict__ b1,
        unsigned short* __restrict__ hbf) {
    __shared__ __align__(16) unsigned short w1t[128 * 136];   // [n][k] padded: 272B stride -> 2-way only
    int tid = threadIdx.x;
    for (int i = tid; i < DIM * DIM; i += 256) {
        int k = i >> 7, n = i & 127;
        w1t[n * 136 + k] = f2bf(W1[i]);
    }
    __syncthreads();
    int w = tid >> 6, lane = tid & 63;
    int lr = lane & 15, q = lane >> 4;
    int row0 = blockIdx.x * 64 + w * 16;
    int rowA = row0 + lr; if (rowA >= N_NODES) rowA = N_NODES - 1;   // clamp; store guarded below
    f32x4 acc[8];
    #pragma unroll
    for (int ct = 0; ct < 8; ct++) acc[ct] = (f32x4){0.f, 0.f, 0.f, 0.f};
    #pragma unroll
    for (int kt = 0; kt < 4; kt++) {
        const float* ap = x + (size_t)rowA * DIM + kt * 32 + q * 8;
        bf16x8 a;
        #pragma unroll
        for (int j = 0; j < 8; j++) a[j] = (__bf16)ap[j];
        #pragma unroll
        for (int ct = 0; ct < 8; ct++) {
            bf16x8 b = __builtin_bit_cast(bf16x8,
                *(const u32x4*)(&w1t[(ct * 16 + lr) * 136 + kt * 32 + q * 8]));
            acc[ct] = __builtin_amdgcn_mfma_f32_16x16x32_bf16(a, b, acc[ct], 0, 0, 0);
        }
    }
    #pragma unroll
    for (int ct = 0; ct < 8; ct++) {
        int col = ct * 16 + lr;
        float bias = b1[col];
        #pragma unroll
        for (int r = 0; r < 4; r++) {
            int row = row0 + q * 4 + r;   // C/D layout: col=lane&15, row=quad*4+reg (m89-verified)
            if (row < N_NODES)
                hbf[(size_t)row * DIM + col] = f2bf(acc[ct][r] + bias);
        }
    }
}

// ---- fused edge MLP + scatter-max. 64 edges/tile, 4 waves x 32 cols.
__global__ __launch_bounds__(256, 2) void edge_kernel(
        const unsigned short* __restrict__ hbf,
        const int* __restrict__ eidx,
        const unsigned short* __restrict__ W2t,
        const unsigned short* __restrict__ W3t,
        const float* __restrict__ b2,
        const float* __restrict__ b3,
        unsigned int* __restrict__ out) {
    __shared__ __align__(16) unsigned short e_lds[64 * 264];    // [edge][256k] pad+8
    __shared__ __align__(16) unsigned short m1_lds[64 * 136];   // [edge][128k] pad+8
    __shared__ int s_src[64];
    __shared__ int s_dst[64];

    int tid = threadIdx.x;
    int w = tid >> 6, lane = tid & 63;
    int lr = lane & 15, q = lane >> 4;

    // register-cached B fragments (fixed cols per wave, amortized over grid-stride loop)
    bf16x8 b2f[2][8], b3f[2][4];
    float b2v[2], b3v[2];
    #pragma unroll
    for (int ct = 0; ct < 2; ct++) {
        int n = (2 * w + ct) * 16 + lr;
        #pragma unroll
        for (int kt = 0; kt < 8; kt++)
            b2f[ct][kt] = __builtin_bit_cast(bf16x8, *(const u32x4*)(&W2t[n * 256 + kt * 32 + q * 8]));
        #pragma unroll
        for (int kt = 0; kt < 4; kt++)
            b3f[ct][kt] = __builtin_bit_cast(bf16x8, *(const u32x4*)(&W3t[n * 128 + kt * 32 + q * 8]));
        b2v[ct] = b2[n];
        b3v[ct] = b3[n];
    }

    for (int tb = blockIdx.x; tb < NTILES; tb += gridDim.x) {
        int eb = tb * 64;
        if (tid < 64) {
            s_src[tid] = eidx[eb + tid];
            s_dst[tid] = eidx[N_EDGES + eb + tid];
        }
        __syncthreads();

        // gather: e[t][0:128]=h_i(dst), e[t][128:256]=h_j(src)-h_i
        #pragma unroll
        for (int it = 0; it < 4; it++) {
            int i = tid + it * 256;
            int t = i >> 4, c = i & 15;
            u32x4 hi4 = *(const u32x4*)(&hbf[(size_t)s_dst[t] * DIM + c * 8]);
            u32x4 hj4 = *(const u32x4*)(&hbf[(size_t)s_src[t] * DIM + c * 8]);
            u32x4 df;
            #pragma unroll
            for (int jj = 0; jj < 4; jj++) {
                unsigned a = hi4[jj], b = hj4[jj];
                float dl = __uint_as_float(b << 16) - __uint_as_float(a << 16);
                float dh = __uint_as_float(b & 0xffff0000u) - __uint_as_float(a & 0xffff0000u);
                df[jj] = (unsigned)f2bf(dl) | ((unsigned)f2bf(dh) << 16);
            }
            *(u32x4*)(&e_lds[t * 264 + c * 8]) = hi4;
            *(u32x4*)(&e_lds[t * 264 + 128 + c * 8]) = df;
        }
        __syncthreads();

        // GEMM1: m1 = relu(e @ W2 + b2), K=256
        f32x4 acc1[4][2];
        #pragma unroll
        for (int rt = 0; rt < 4; rt++)
            #pragma unroll
            for (int ct = 0; ct < 2; ct++) acc1[rt][ct] = (f32x4){0.f, 0.f, 0.f, 0.f};
        #pragma unroll
        for (int kt = 0; kt < 8; kt++) {
            #pragma unroll
            for (int rt = 0; rt < 4; rt++) {
                bf16x8 a = __builtin_bit_cast(bf16x8,
                    *(const u32x4*)(&e_lds[(rt * 16 + lr) * 264 + kt * 32 + q * 8]));
                acc1[rt][0] = __builtin_amdgcn_mfma_f32_16x16x32_bf16(a, b2f[0][kt], acc1[rt][0], 0, 0, 0);
                acc1[rt][1] = __builtin_amdgcn_mfma_f32_16x16x32_bf16(a, b2f[1][kt], acc1[rt][1], 0, 0, 0);
            }
        }
        #pragma unroll
        for (int rt = 0; rt < 4; rt++) {
            #pragma unroll
            for (int ct = 0; ct < 2; ct++) {
                int col = (2 * w + ct) * 16 + lr;
                #pragma unroll
                for (int r = 0; r < 4; r++) {
                    float v = fmaxf(acc1[rt][ct][r] + b2v[ct], 0.f);
                    m1_lds[(rt * 16 + q * 4 + r) * 136 + col] = f2bf(v);
                }
            }
        }
        __syncthreads();

        // GEMM2: m2 = relu(m1 @ W3 + b3), K=128; scatter-max
        f32x4 acc2[4][2];
        #pragma unroll
        for (int rt = 0; rt < 4; rt++)
            #pragma unroll
            for (int ct = 0; ct < 2; ct++) acc2[rt][ct] = (f32x4){0.f, 0.f, 0.f, 0.f};
        #pragma unroll
        for (int kt = 0; kt < 4; kt++) {
            #pragma unroll
            for (int rt = 0; rt < 4; rt++) {
                bf16x8 a = __builtin_bit_cast(bf16x8,
                    *(const u32x4*)(&m1_lds[(rt * 16 + lr) * 136 + kt * 32 + q * 8]));
                acc2[rt][0] = __builtin_amdgcn_mfma_f32_16x16x32_bf16(a, b3f[0][kt], acc2[rt][0], 0, 0, 0);
                acc2[rt][1] = __builtin_amdgcn_mfma_f32_16x16x32_bf16(a, b3f[1][kt], acc2[rt][1], 0, 0, 0);
            }
        }
        #pragma unroll
        for (int rt = 0; rt < 4; rt++) {
            #pragma unroll
            for (int ct = 0; ct < 2; ct++) {
                int col = (2 * w + ct) * 16 + lr;
                #pragma unroll
                for (int r = 0; r < 4; r++) {
                    float v = fmaxf(acc2[rt][ct][r] + b3v[ct], 0.f);
                    int node = s_dst[rt * 16 + q * 4 + r];
                    // v >= 0 and out zero-initialized: uint-compare == float-compare
                    atomicMax(&out[(size_t)node * DIM + col], __float_as_uint(v));
                }
            }
        }
        __syncthreads();   // protect e_lds/s_dst before next iteration overwrites
    }
}

extern "C" void kernel_launch(void* const* d_in, const int* in_sizes, int n_in,
                              void* d_out, int out_size, void* d_ws, size_t ws_size,
                              hipStream_t stream) {
    const float* x  = (const float*)d_in[0];
    const int* eidx = (const int*)d_in[1];
    const float* W1 = (const float*)d_in[2];
    const float* b1 = (const float*)d_in[3];
    const float* W2 = (const float*)d_in[4];
    const float* b2 = (const float*)d_in[5];
    const float* W3 = (const float*)d_in[6];
    const float* b3 = (const float*)d_in[7];

    unsigned short* hbf = (unsigned short*)d_ws;                                   // 12.8 MB
    unsigned short* W2t = (unsigned short*)((char*)d_ws + 12800000);               // 64 KB
    unsigned short* W3t = (unsigned short*)((char*)d_ws + 12800000 + 65536);       // 32 KB

    hipMemsetAsync(d_out, 0, (size_t)N_NODES * DIM * sizeof(float), stream);
    convert_w_kernel<<<192, 256, 0, stream>>>(W2, W3, W2t, W3t);
    lin1_kernel<<<(N_NODES + 63) / 64, 256, 0, stream>>>(x, W1, b1, hbf);
    edge_kernel<<<2048, 256, 0, stream>>>(hbf, eidx, W2t, W3t, b2, b3, (unsigned int*)d_out);
}